// Round 15
// baseline (117.140 us; speedup 1.0000x reference)
//
#include <hip/hip_runtime.h>
#include <math.h>

#define NHEAD 16
#define HD 64
#define DMODEL 1024
#define SEQ 1024
#define BATCH 8
#define ROWS (BATCH * SEQ)   // 8192

typedef __attribute__((ext_vector_type(8))) short bf16x8;
typedef __attribute__((ext_vector_type(8))) short short8v;
typedef __attribute__((ext_vector_type(4))) float f32x4;
typedef __attribute__((ext_vector_type(16))) float f32x16;
typedef __attribute__((ext_vector_type(4))) short short4v;
typedef __attribute__((ext_vector_type(4))) unsigned int uint32x4;

__device__ __forceinline__ unsigned short f2bf(float f) {
    unsigned u = __builtin_bit_cast(unsigned, f);
    u += 0x7FFF + ((u >> 16) & 1);          // RNE
    return (unsigned short)(u >> 16);
}

__device__ __forceinline__ float fexp2(float x) {
#if __has_builtin(__builtin_amdgcn_exp2f)
    return __builtin_amdgcn_exp2f(x);
#else
    return __expf(x * 0.6931471805599453f);
#endif
}

__device__ __forceinline__ void gload16(const void* g, void* l) {
    __builtin_amdgcn_global_load_lds(
        (const __attribute__((address_space(1))) unsigned int*)g,
        (__attribute__((address_space(3))) unsigned int*)l, 16, 0, 0);
}

// ---------------------------------------------------------------------------
// Fused f32->bf16 converts for all 6 inputs in ONE launch (segmented grid).
// ---------------------------------------------------------------------------
#define QSCALE 0.18033688011112042f
__global__ __launch_bounds__(256) void cvt_all(const float* __restrict__ x,
                                               const float* __restrict__ Ws,
                                               const float* __restrict__ Wo,
                                               const float* __restrict__ Wq,
                                               const float* __restrict__ Wk,
                                               const float* __restrict__ Wv,
                                               unsigned short* __restrict__ xb,
                                               unsigned short* __restrict__ wsb,
                                               unsigned short* __restrict__ wob,
                                               unsigned short* __restrict__ wqb,
                                               unsigned short* __restrict__ wkb,
                                               unsigned short* __restrict__ wvb) {
    int bid = blockIdx.x;
    const float* src; unsigned short* dst; float scale = 1.f;
    if (bid < 4096)      { src = x;  dst = xb;  }
    else if (bid < 4608) { src = Ws; dst = wsb; bid -= 4096; }
    else if (bid < 5120) { src = Wo; dst = wob; bid -= 4608; }
    else if (bid < 5152) { src = Wq; dst = wqb; bid -= 5120; scale = QSCALE; }
    else if (bid < 5184) { src = Wk; dst = wkb; bid -= 5152; }
    else                 { src = Wv; dst = wvb; bid -= 5184; }
    int i = (bid * 256 + threadIdx.x) * 8;
    float4 a = *(const float4*)(src + i);
    float4 b = *(const float4*)(src + i + 4);
    short8v o;
    o[0] = (short)f2bf(a.x * scale); o[1] = (short)f2bf(a.y * scale);
    o[2] = (short)f2bf(a.z * scale); o[3] = (short)f2bf(a.w * scale);
    o[4] = (short)f2bf(b.x * scale); o[5] = (short)f2bf(b.y * scale);
    o[6] = (short)f2bf(b.z * scale); o[7] = (short)f2bf(b.w * scale);
    *(short8v*)(dst + i) = o;
}

// ---------------------------------------------------------------------------
// Fused GEMM1 + QKV — 8 waves (512 thr). Epilogue stages BOTH heads' weights
// once (48 KB) -> single barrier, uninterrupted per-head compute.
// ---------------------------------------------------------------------------
__global__ __launch_bounds__(512) void gemm1_qkv(const unsigned short* __restrict__ A,
                                                 const unsigned short* __restrict__ B,
                                                 const unsigned short* __restrict__ wqb,
                                                 const unsigned short* __restrict__ wkb,
                                                 const unsigned short* __restrict__ wvb,
                                                 unsigned short* __restrict__ qb,
                                                 unsigned short* __restrict__ kbuf,
                                                 unsigned short* __restrict__ vT) {
    __shared__ char lds[81920];   // main loop: 64K dbuf; epilogue: 32K xp + 48K weights
    const int tid  = threadIdx.x;
    const int w    = tid >> 6;            // 0..7
    const int lane = tid & 63;
    const int lr   = lane & 15, lg = lane >> 4;
    const int wr   = w >> 1,  wc = w & 1;
    const int m0   = blockIdx.x * 128;
    const int n0   = blockIdx.y * 128;
    const int K    = DMODEL;

    f32x4 acc[2][4] = {};

    const int srow   = lane >> 3;
    const int swbyte = ((lane & 7) ^ srow) << 4;

#define G1_STAGE(buf, k0)                                                          \
    {                                                                              \
        _Pragma("unroll")                                                          \
        for (int c = 0; c < 2; ++c) {                                              \
            int chunk = w * 2 + c;                                                 \
            int row   = chunk * 8 + srow;                                          \
            gload16((const char*)A + ((size_t)(m0 + row) * K + (k0)) * 2 + swbyte, \
                    lds + (buf) * 16384 + chunk * 1024);                           \
            gload16((const char*)B + ((size_t)(n0 + row) * K + (k0)) * 2 + swbyte, \
                    lds + 32768 + (buf) * 16384 + chunk * 1024);                   \
        }                                                                          \
    }

    G1_STAGE(0, 0);
    __syncthreads();

    int cur = 0;
    for (int t = 0; t < K / 64; ++t) {
        if (t + 1 < K / 64) G1_STAGE(cur ^ 1, (t + 1) * 64);

#pragma unroll
        for (int k2 = 0; k2 < 2; ++k2) {
            bf16x8 af[2], bg[4];
#pragma unroll
            for (int f = 0; f < 2; ++f) {
                int row = wr * 32 + f * 16 + lr;
                af[f] = *(const bf16x8*)(lds + cur * 16384 + row * 128 +
                                         ((k2 * 64 + lg * 16) ^ ((row & 7) << 4)));
            }
#pragma unroll
            for (int g = 0; g < 4; ++g) {
                int row = wc * 64 + g * 16 + lr;
                bg[g] = *(const bf16x8*)(lds + 32768 + cur * 16384 + row * 128 +
                                         ((k2 * 64 + lg * 16) ^ ((row & 7) << 4)));
            }
#pragma unroll
            for (int f = 0; f < 2; ++f)
#pragma unroll
                for (int g = 0; g < 4; ++g)
                    acc[f][g] = __builtin_amdgcn_mfma_f32_16x16x32_bf16(af[f], bg[g],
                                                                        acc[f][g], 0, 0, 0);
        }
        __syncthreads();
        cur ^= 1;
    }
#undef G1_STAGE

    // ---- epilogue: xp tile -> LDS bf16 [128 rows][256 B], swizzled ----
#pragma unroll
    for (int f = 0; f < 2; ++f)
#pragma unroll
        for (int g = 0; g < 4; ++g)
#pragma unroll
            for (int r = 0; r < 4; ++r) {
                int mrow = wr * 32 + f * 16 + lg * 4 + r;
                int ncol = wc * 64 + g * 16 + lr;
                *(unsigned short*)(lds + mrow * 256 + ((ncol * 2) ^ ((mrow & 7) << 4))) =
                    f2bf(acc[f][g][r]);
            }

    // ---- stage BOTH heads' weights: 48 chunks over 8 waves ----
#pragma unroll
    for (int i = 0; i < 6; ++i) {
        int c   = w * 6 + i;                   // 0..47
        int p   = c >> 3;                      // 0..5 = (head hh)*3 + proj
        int rc  = c & 7;
        int row = rc * 8 + srow;
        int hh  = p >= 3;
        int pj  = p - 3 * hh;
        int h   = blockIdx.y * 2 + hh;
        const unsigned short* ws = (pj == 0) ? wqb : (pj == 1) ? wkb : wvb;
        gload16((const char*)ws + ((size_t)(h * 64 + row) * 64) * 2 + swbyte,
                lds + 32768 + p * 8192 + rc * 1024);
    }
    __syncthreads();   // xp writes + weight loads all visible

    const int b  = m0 >> 10;
    const int sl = m0 & 1023;

#pragma unroll
    for (int hh = 0; hh < 2; ++hh) {
        const int h = blockIdx.y * 2 + hh;
        f32x4 a2[3][4] = {};
#pragma unroll
        for (int k2 = 0; k2 < 2; ++k2) {
            int arow = w * 16 + lr;
            bf16x8 af = *(const bf16x8*)(lds + arow * 256 +
                                         ((hh * 128 + k2 * 64 + lg * 16) ^ ((arow & 7) << 4)));
#pragma unroll
            for (int p = 0; p < 3; ++p)
#pragma unroll
                for (int g = 0; g < 4; ++g) {
                    int o = g * 16 + lr;
                    bf16x8 bg = *(const bf16x8*)(lds + 32768 + (hh * 3 + p) * 8192 + o * 128 +
                                                 ((k2 * 64 + lg * 16) ^ ((o & 7) << 4)));
                    a2[p][g] = __builtin_amdgcn_mfma_f32_16x16x32_bf16(af, bg,
                                                                       a2[p][g], 0, 0, 0);
                }
        }

#pragma unroll
        for (int g = 0; g < 4; ++g) {
#pragma unroll
            for (int r = 0; r < 4; ++r) {
                size_t idx = (size_t)(m0 + w * 16 + lg * 4 + r) * DMODEL +
                             h * 64 + g * 16 + lr;
                qb[idx]   = f2bf(a2[0][g][r]);
                kbuf[idx] = f2bf(a2[1][g][r]);
            }
            short4v pv;
#pragma unroll
            for (int r = 0; r < 4; ++r) pv[r] = (short)f2bf(a2[2][g][r]);
            size_t o = (size_t)(b * 16 + h) * 64 + g * 16 + lr;
            *(short4v*)(vT + o * SEQ + sl + w * 16 + lg * 4) = pv;
        }
    }
}

// ---------------------------------------------------------------------------
// bf16 MFMA GEMM (f32 out) — GEMM2, 8 waves (512 thr), 32x64 per wave.
// ---------------------------------------------------------------------------
__global__ __launch_bounds__(512) void gemm_bf16(const unsigned short* __restrict__ A,
                                                 const unsigned short* __restrict__ B,
                                                 float* __restrict__ Cf,
                                                 int M, int N, int K) {
    __shared__ char sA[2][16384];
    __shared__ char sB[2][16384];
    const int tid  = threadIdx.x;
    const int w    = tid >> 6;
    const int lane = tid & 63;
    const int lr   = lane & 15, lg = lane >> 4;
    const int wr   = w >> 1,  wc = w & 1;
    const int m0   = blockIdx.x * 128;
    const int n0   = blockIdx.y * 128;

    f32x4 acc[2][4] = {};

    const int srow   = lane >> 3;
    const int swbyte = ((lane & 7) ^ srow) << 4;
    const int nt     = K / 64;

#define GEMM_STAGE(buf, k0)                                                        \
    {                                                                              \
        _Pragma("unroll")                                                          \
        for (int c = 0; c < 2; ++c) {                                              \
            int chunk = w * 2 + c;                                                 \
            int row   = chunk * 8 + srow;                                          \
            gload16((const char*)A + ((size_t)(m0 + row) * K + (k0)) * 2 + swbyte, \
                    sA[buf] + chunk * 1024);                                       \
            gload16((const char*)B + ((size_t)(n0 + row) * K + (k0)) * 2 + swbyte, \
                    sB[buf] + chunk * 1024);                                       \
        }                                                                          \
    }

    GEMM_STAGE(0, 0);
    __syncthreads();

    int cur = 0;
    for (int t = 0; t < nt; ++t) {
        if (t + 1 < nt) GEMM_STAGE(cur ^ 1, (t + 1) * 64);

#pragma unroll
        for (int k2 = 0; k2 < 2; ++k2) {
            bf16x8 af[2], bg[4];
#pragma unroll
            for (int f = 0; f < 2; ++f) {
                int row = wr * 32 + f * 16 + lr;
                af[f] = *(const bf16x8*)(sA[cur] + row * 128 +
                                         ((k2 * 64 + lg * 16) ^ ((row & 7) << 4)));
            }
#pragma unroll
            for (int g = 0; g < 4; ++g) {
                int row = wc * 64 + g * 16 + lr;
                bg[g] = *(const bf16x8*)(sB[cur] + row * 128 +
                                         ((k2 * 64 + lg * 16) ^ ((row & 7) << 4)));
            }
#pragma unroll
            for (int f = 0; f < 2; ++f)
#pragma unroll
                for (int g = 0; g < 4; ++g)
                    acc[f][g] = __builtin_amdgcn_mfma_f32_16x16x32_bf16(af[f], bg[g],
                                                                        acc[f][g], 0, 0, 0);
        }
        __syncthreads();
        cur ^= 1;
    }
#undef GEMM_STAGE

#pragma unroll
    for (int f = 0; f < 2; ++f)
#pragma unroll
        for (int g = 0; g < 4; ++g)
#pragma unroll
            for (int r = 0; r < 4; ++r)
                Cf[(size_t)(m0 + wr * 32 + f * 16 + lg * 4 + r) * N +
                   n0 + wc * 64 + g * 16 + lr] = acc[f][g][r];
}

// ---------------------------------------------------------------------------
// MFMA flash attention v12: pair-wise barriers (17->9) with sched_barrier(0)
// BETWEEN the two tiles — keeps live ranges separate so VGPR stays ~64
// (r13's schedule without its register explosion). Unnormalized softmax.
// ---------------------------------------------------------------------------
__global__ __launch_bounds__(512) void attn_mfma(const unsigned short* __restrict__ qb,
                                                 const unsigned short* __restrict__ kb,
                                                 const unsigned short* __restrict__ vT,
                                                 unsigned short* __restrict__ ob) {
    __shared__ unsigned short sK[4][4096];   // 2 pair-slots x 2 tiles
    __shared__ unsigned short sV[4][4096];

    const int tid  = threadIdx.x;
    const int w    = tid >> 6;
    const int lane = tid & 63;
    const int ql   = lane & 31;
    const int hl   = lane >> 5;
    const int bh   = blockIdx.x;
    const int b    = bh >> 4, h = bh & 15;
    const int s0   = blockIdx.y * 256;
    const int NP   = SEQ / 128;              // 8 pairs

    const unsigned short* qrow = qb + ((size_t)(b * SEQ + s0 + w * 32 + ql) * DMODEL + h * 64);
    bf16x8 qf[4];
#pragma unroll
    for (int s = 0; s < 4; ++s)
        qf[s] = *(const bf16x8*)(qrow + 16 * s + 8 * hl);

    f32x16 acc0 = {}, acc1 = {};
    float l0 = 0.f, l1 = 0.f, l2 = 0.f, l3 = 0.f;

    const int srow = lane >> 3;
    const int ssw  = ((lane & 7) << 4) ^ (srow << 4);
    const int swz  = (ql & 7) << 4;
    int byos[4];
#pragma unroll
    for (int s = 0; s < 4; ++s) byos[s] = (32 * s + 16 * hl) ^ swz;

#define ATTN_STAGE(buf, kt)                                                          \
    {                                                                                \
        int row = w * 8 + srow;                                                      \
        gload16((const char*)kb +                                                    \
                    (((size_t)(b * SEQ + (kt) * 64 + row) * DMODEL + h * 64) * 2) + ssw, \
                (char*)sK[buf] + w * 1024);                                          \
        gload16((const char*)vT +                                                    \
                    (((size_t)(bh * 64 + row) * SEQ + (kt) * 64) * 2) + ssw,         \
                (char*)sV[buf] + w * 1024);                                          \
    }

#define TILE_P(stv, PF0, PF1)                                                       \
        {                                                                           \
            float p_[16];                                                           \
            _Pragma("unroll")                                                       \
            for (int i = 0; i < 16; ++i) p_[i] = fexp2(stv[i]);                     \
            _Pragma("unroll")                                                       \
            for (int i = 0; i < 4; ++i) {                                           \
                l0 += p_[4 * i];     l1 += p_[4 * i + 1];                           \
                l2 += p_[4 * i + 2]; l3 += p_[4 * i + 3];                           \
            }                                                                       \
            unsigned pk_[8];                                                        \
            _Pragma("unroll")                                                       \
            for (int i = 0; i < 8; ++i)                                             \
                asm("v_cvt_pk_bf16_f32 %0, %1, %2"                                  \
                    : "=v"(pk_[i]) : "v"(p_[2 * i]), "v"(p_[2 * i + 1]));           \
            auto rA = __builtin_amdgcn_permlane32_swap(pk_[0], pk_[2], false, false); \
            auto rB = __builtin_amdgcn_permlane32_swap(pk_[1], pk_[3], false, false); \
            auto rC = __builtin_amdgcn_permlane32_swap(pk_[4], pk_[6], false, false); \
            auto rD = __builtin_amdgcn_permlane32_swap(pk_[5], pk_[7], false, false); \
            uint32x4 f0, f1;                                                        \
            f0[0] = rA[0]; f0[1] = rB[0]; f0[2] = rA[1]; f0[3] = rB[1];             \
            f1[0] = rC[0]; f1[1] = rD[0]; f1[2] = rC[1]; f1[3] = rD[1];             \
            PF0 = __builtin_bit_cast(bf16x8, f0);                                   \
            PF1 = __builtin_bit_cast(bf16x8, f1);                                   \
        }

#define ATTN_TILE(cb)                                                               \
    {                                                                               \
        f32x16 st0 = {}, st1 = {};                                                  \
        __builtin_amdgcn_s_setprio(1);                                              \
        _Pragma("unroll")                                                           \
        for (int s = 0; s < 4; ++s) {                                               \
            bf16x8 kf0 = *(const bf16x8*)((const char*)sK[cb] + ql * 128 + byos[s]);\
            bf16x8 kf1 = *(const bf16x8*)((const char*)sK[cb] + (32 + ql) * 128 + byos[s]); \
            st0 = __builtin_amdgcn_mfma_f32_32x32x16_bf16(kf0, qf[s], st0, 0, 0, 0);\
            st1 = __builtin_amdgcn_mfma_f32_32x32x16_bf16(kf1, qf[s], st1, 0, 0, 0);\
        }                                                                           \
        __builtin_amdgcn_s_setprio(0);                                              \
        bf16x8 pf[4];                                                               \
        TILE_P(st0, pf[0], pf[1]);                                                  \
        TILE_P(st1, pf[2], pf[3]);                                                  \
        __builtin_amdgcn_s_setprio(1);                                              \
        _Pragma("unroll")                                                           \
        for (int s = 0; s < 4; ++s) {                                               \
            bf16x8 vf0 = *(const bf16x8*)((const char*)sV[cb] + ql * 128 + byos[s]);\
            bf16x8 vf1 = *(const bf16x8*)((const char*)sV[cb] + (32 + ql) * 128 + byos[s]); \
            acc0 = __builtin_amdgcn_mfma_f32_32x32x16_bf16(vf0, pf[s], acc0, 0, 0, 0); \
            acc1 = __builtin_amdgcn_mfma_f32_32x32x16_bf16(vf1, pf[s], acc1, 0, 0, 0); \
        }                                                                           \
        __builtin_amdgcn_s_setprio(0);                                              \
    }

    // prologue: stage pair 0 into slot 0 (tiles 0,1)
    ATTN_STAGE(0, 0);
    ATTN_STAGE(1, 1);
    asm volatile("s_waitcnt vmcnt(0)" ::: "memory");
    __builtin_amdgcn_s_barrier();
    __builtin_amdgcn_sched_barrier(0);

    for (int P = 0; P < NP; ++P) {
        const int slot = (P & 1) << 1;           // 0 or 2
        if (P + 1 < NP) {
            ATTN_STAGE(slot ^ 2, 2 * (P + 1));
            ATTN_STAGE((slot ^ 2) + 1, 2 * (P + 1) + 1);
        }
        __builtin_amdgcn_sched_barrier(0);       // issues stay above compute

        ATTN_TILE(slot);                         // tile 2P
        __builtin_amdgcn_sched_barrier(0);       // pin: keep tiles sequential (VGPR flat)
        ATTN_TILE(slot + 1);                     // tile 2P+1

        asm volatile("s_waitcnt vmcnt(0)" ::: "memory");
        __builtin_amdgcn_s_barrier();
        __builtin_amdgcn_sched_barrier(0);
    }
#undef ATTN_TILE
#undef TILE_P
#undef ATTN_STAGE

    // ---- epilogue: combine l partials + cross-half, normalize, store ----
    float l_ = (l0 + l1) + (l2 + l3);
    float lf = l_ + __shfl_xor(l_, 32, 64);
    float inv = 1.f / lf;
    const size_t rowbase = (size_t)(b * SEQ + s0 + w * 32 + ql) * DMODEL + h * 64;
#pragma unroll
    for (int g = 0; g < 4; ++g) {
        short4v o0, o1;
#pragma unroll
        for (int r = 0; r < 4; ++r) {
            o0[r] = (short)f2bf(acc0[4 * g + r] * inv);
            o1[r] = (short)f2bf(acc1[4 * g + r] * inv);
        }
        int d = 8 * g + 4 * hl;
        *(short4v*)(ob + rowbase + d)      = o0;
        *(short4v*)(ob + rowbase + 32 + d) = o1;
    }
}

// ---------------------------------------------------------------------------
extern "C" void kernel_launch(void* const* d_in, const int* in_sizes, int n_in,
                              void* d_out, int out_size, void* d_ws, size_t ws_size,
                              hipStream_t stream) {
    const float* x       = (const float*)d_in[0];
    const float* W_split = (const float*)d_in[1];
    const float* W_out   = (const float*)d_in[2];
    const float* Wq      = (const float*)d_in[3];
    const float* Wk      = (const float*)d_in[4];
    const float* Wv      = (const float*)d_in[5];
    float* out = (float*)d_out;

    unsigned short* xb  = (unsigned short*)d_ws;                    // 16 MB
    unsigned short* obb = xb;                                       // alias (xb dead post-gemm1)
    unsigned short* wsb = xb + (size_t)ROWS * DMODEL;               // 2 MB
    unsigned short* wob = wsb + (size_t)DMODEL * DMODEL;            // 2 MB
    unsigned short* qbuf= wob + (size_t)DMODEL * DMODEL;            // 16 MB
    unsigned short* kbuf= qbuf + (size_t)ROWS * DMODEL;             // 16 MB
    unsigned short* vT  = kbuf + (size_t)ROWS * DMODEL;             // 16 MB
    unsigned short* wqb = vT + (size_t)ROWS * DMODEL;               // 128 KB
    unsigned short* wkb = wqb + (size_t)NHEAD * HD * HD;
    unsigned short* wvb = wkb + (size_t)NHEAD * HD * HD;

    // 0) all converts in one launch
    cvt_all<<<dim3(5216), dim3(256), 0, stream>>>(x, W_split, W_out, Wq, Wk, Wv,
                                                  xb, wsb, wob, wqb, wkb, wvb);
    // 1+2) fused GEMM1+QKV
    gemm1_qkv<<<dim3(ROWS / 128, DMODEL / 128), dim3(512), 0, stream>>>(
        xb, wsb, wqb, wkb, wvb, qbuf, kbuf, vT);
    // 3) flash attention v12
    attn_mfma<<<dim3(BATCH * NHEAD, SEQ / 256), dim3(512), 0, stream>>>(qbuf, kbuf, vT, obb);
    // 4) out = obb @ W_out^T (f32)
    gemm_bf16<<<dim3(ROWS / 128, DMODEL / 128), dim3(512), 0, stream>>>(
        obb, wob, out, ROWS, DMODEL, DMODEL);
}

// Round 16
// 110.505 us; speedup vs baseline: 1.0600x; 1.0600x over previous
//
#include <hip/hip_runtime.h>
#include <math.h>

#define NHEAD 16
#define HD 64
#define DMODEL 1024
#define SEQ 1024
#define BATCH 8
#define ROWS (BATCH * SEQ)   // 8192

typedef __attribute__((ext_vector_type(8))) short bf16x8;
typedef __attribute__((ext_vector_type(8))) short short8v;
typedef __attribute__((ext_vector_type(4))) float f32x4;
typedef __attribute__((ext_vector_type(16))) float f32x16;
typedef __attribute__((ext_vector_type(4))) short short4v;
typedef __attribute__((ext_vector_type(4))) unsigned int uint32x4;

__device__ __forceinline__ unsigned short f2bf(float f) {
    unsigned u = __builtin_bit_cast(unsigned, f);
    u += 0x7FFF + ((u >> 16) & 1);          // RNE
    return (unsigned short)(u >> 16);
}

__device__ __forceinline__ float fexp2(float x) {
#if __has_builtin(__builtin_amdgcn_exp2f)
    return __builtin_amdgcn_exp2f(x);
#else
    return __expf(x * 0.6931471805599453f);
#endif
}

__device__ __forceinline__ void gload16(const void* g, void* l) {
    __builtin_amdgcn_global_load_lds(
        (const __attribute__((address_space(1))) unsigned int*)g,
        (__attribute__((address_space(3))) unsigned int*)l, 16, 0, 0);
}

// ---------------------------------------------------------------------------
// Fused f32->bf16 converts for all 6 inputs in ONE launch (segmented grid).
// ---------------------------------------------------------------------------
#define QSCALE 0.18033688011112042f
__global__ __launch_bounds__(256) void cvt_all(const float* __restrict__ x,
                                               const float* __restrict__ Ws,
                                               const float* __restrict__ Wo,
                                               const float* __restrict__ Wq,
                                               const float* __restrict__ Wk,
                                               const float* __restrict__ Wv,
                                               unsigned short* __restrict__ xb,
                                               unsigned short* __restrict__ wsb,
                                               unsigned short* __restrict__ wob,
                                               unsigned short* __restrict__ wqb,
                                               unsigned short* __restrict__ wkb,
                                               unsigned short* __restrict__ wvb) {
    int bid = blockIdx.x;
    const float* src; unsigned short* dst; float scale = 1.f;
    if (bid < 4096)      { src = x;  dst = xb;  }
    else if (bid < 4608) { src = Ws; dst = wsb; bid -= 4096; }
    else if (bid < 5120) { src = Wo; dst = wob; bid -= 4608; }
    else if (bid < 5152) { src = Wq; dst = wqb; bid -= 5120; scale = QSCALE; }
    else if (bid < 5184) { src = Wk; dst = wkb; bid -= 5152; }
    else                 { src = Wv; dst = wvb; bid -= 5184; }
    int i = (bid * 256 + threadIdx.x) * 8;
    float4 a = *(const float4*)(src + i);
    float4 b = *(const float4*)(src + i + 4);
    short8v o;
    o[0] = (short)f2bf(a.x * scale); o[1] = (short)f2bf(a.y * scale);
    o[2] = (short)f2bf(a.z * scale); o[3] = (short)f2bf(a.w * scale);
    o[4] = (short)f2bf(b.x * scale); o[5] = (short)f2bf(b.y * scale);
    o[6] = (short)f2bf(b.z * scale); o[7] = (short)f2bf(b.w * scale);
    *(short8v*)(dst + i) = o;
}

// ---------------------------------------------------------------------------
// Fused GEMM1 + QKV — 8 waves (512 thr). Epilogue stages BOTH heads' weights
// once (48 KB) -> single barrier, uninterrupted per-head compute. (r15)
// ---------------------------------------------------------------------------
__global__ __launch_bounds__(512) void gemm1_qkv(const unsigned short* __restrict__ A,
                                                 const unsigned short* __restrict__ B,
                                                 const unsigned short* __restrict__ wqb,
                                                 const unsigned short* __restrict__ wkb,
                                                 const unsigned short* __restrict__ wvb,
                                                 unsigned short* __restrict__ qb,
                                                 unsigned short* __restrict__ kbuf,
                                                 unsigned short* __restrict__ vT) {
    __shared__ char lds[81920];
    const int tid  = threadIdx.x;
    const int w    = tid >> 6;
    const int lane = tid & 63;
    const int lr   = lane & 15, lg = lane >> 4;
    const int wr   = w >> 1,  wc = w & 1;
    const int m0   = blockIdx.x * 128;
    const int n0   = blockIdx.y * 128;
    const int K    = DMODEL;

    f32x4 acc[2][4] = {};

    const int srow   = lane >> 3;
    const int swbyte = ((lane & 7) ^ srow) << 4;

#define G1_STAGE(buf, k0)                                                          \
    {                                                                              \
        _Pragma("unroll")                                                          \
        for (int c = 0; c < 2; ++c) {                                              \
            int chunk = w * 2 + c;                                                 \
            int row   = chunk * 8 + srow;                                          \
            gload16((const char*)A + ((size_t)(m0 + row) * K + (k0)) * 2 + swbyte, \
                    lds + (buf) * 16384 + chunk * 1024);                           \
            gload16((const char*)B + ((size_t)(n0 + row) * K + (k0)) * 2 + swbyte, \
                    lds + 32768 + (buf) * 16384 + chunk * 1024);                   \
        }                                                                          \
    }

    G1_STAGE(0, 0);
    __syncthreads();

    int cur = 0;
    for (int t = 0; t < K / 64; ++t) {
        if (t + 1 < K / 64) G1_STAGE(cur ^ 1, (t + 1) * 64);

#pragma unroll
        for (int k2 = 0; k2 < 2; ++k2) {
            bf16x8 af[2], bg[4];
#pragma unroll
            for (int f = 0; f < 2; ++f) {
                int row = wr * 32 + f * 16 + lr;
                af[f] = *(const bf16x8*)(lds + cur * 16384 + row * 128 +
                                         ((k2 * 64 + lg * 16) ^ ((row & 7) << 4)));
            }
#pragma unroll
            for (int g = 0; g < 4; ++g) {
                int row = wc * 64 + g * 16 + lr;
                bg[g] = *(const bf16x8*)(lds + 32768 + cur * 16384 + row * 128 +
                                         ((k2 * 64 + lg * 16) ^ ((row & 7) << 4)));
            }
#pragma unroll
            for (int f = 0; f < 2; ++f)
#pragma unroll
                for (int g = 0; g < 4; ++g)
                    acc[f][g] = __builtin_amdgcn_mfma_f32_16x16x32_bf16(af[f], bg[g],
                                                                        acc[f][g], 0, 0, 0);
        }
        __syncthreads();
        cur ^= 1;
    }
#undef G1_STAGE

    // ---- epilogue: xp tile -> LDS bf16 [128 rows][256 B], swizzled ----
#pragma unroll
    for (int f = 0; f < 2; ++f)
#pragma unroll
        for (int g = 0; g < 4; ++g)
#pragma unroll
            for (int r = 0; r < 4; ++r) {
                int mrow = wr * 32 + f * 16 + lg * 4 + r;
                int ncol = wc * 64 + g * 16 + lr;
                *(unsigned short*)(lds + mrow * 256 + ((ncol * 2) ^ ((mrow & 7) << 4))) =
                    f2bf(acc[f][g][r]);
            }

    // ---- stage BOTH heads' weights: 48 chunks over 8 waves ----
#pragma unroll
    for (int i = 0; i < 6; ++i) {
        int c   = w * 6 + i;
        int p   = c >> 3;
        int rc  = c & 7;
        int row = rc * 8 + srow;
        int hh  = p >= 3;
        int pj  = p - 3 * hh;
        int h   = blockIdx.y * 2 + hh;
        const unsigned short* ws = (pj == 0) ? wqb : (pj == 1) ? wkb : wvb;
        gload16((const char*)ws + ((size_t)(h * 64 + row) * 64) * 2 + swbyte,
                lds + 32768 + p * 8192 + rc * 1024);
    }
    __syncthreads();

    const int b  = m0 >> 10;
    const int sl = m0 & 1023;

#pragma unroll
    for (int hh = 0; hh < 2; ++hh) {
        const int h = blockIdx.y * 2 + hh;
        f32x4 a2[3][4] = {};
#pragma unroll
        for (int k2 = 0; k2 < 2; ++k2) {
            int arow = w * 16 + lr;
            bf16x8 af = *(const bf16x8*)(lds + arow * 256 +
                                         ((hh * 128 + k2 * 64 + lg * 16) ^ ((arow & 7) << 4)));
#pragma unroll
            for (int p = 0; p < 3; ++p)
#pragma unroll
                for (int g = 0; g < 4; ++g) {
                    int o = g * 16 + lr;
                    bf16x8 bg = *(const bf16x8*)(lds + 32768 + (hh * 3 + p) * 8192 + o * 128 +
                                                 ((k2 * 64 + lg * 16) ^ ((o & 7) << 4)));
                    a2[p][g] = __builtin_amdgcn_mfma_f32_16x16x32_bf16(af, bg,
                                                                       a2[p][g], 0, 0, 0);
                }
        }

#pragma unroll
        for (int g = 0; g < 4; ++g) {
#pragma unroll
            for (int r = 0; r < 4; ++r) {
                size_t idx = (size_t)(m0 + w * 16 + lg * 4 + r) * DMODEL +
                             h * 64 + g * 16 + lr;
                qb[idx]   = f2bf(a2[0][g][r]);
                kbuf[idx] = f2bf(a2[1][g][r]);
            }
            short4v pv;
#pragma unroll
            for (int r = 0; r < 4; ++r) pv[r] = (short)f2bf(a2[2][g][r]);
            size_t o = (size_t)(b * 16 + h) * 64 + g * 16 + lr;
            *(short4v*)(vT + o * SEQ + sl + w * 16 + lg * 4) = pv;
        }
    }
}

// ---------------------------------------------------------------------------
// bf16 MFMA GEMM (f32 out) — GEMM2, 8 waves (512 thr), 32x64 per wave.
// ---------------------------------------------------------------------------
__global__ __launch_bounds__(512) void gemm_bf16(const unsigned short* __restrict__ A,
                                                 const unsigned short* __restrict__ B,
                                                 float* __restrict__ Cf,
                                                 int M, int N, int K) {
    __shared__ char sA[2][16384];
    __shared__ char sB[2][16384];
    const int tid  = threadIdx.x;
    const int w    = tid >> 6;
    const int lane = tid & 63;
    const int lr   = lane & 15, lg = lane >> 4;
    const int wr   = w >> 1,  wc = w & 1;
    const int m0   = blockIdx.x * 128;
    const int n0   = blockIdx.y * 128;

    f32x4 acc[2][4] = {};

    const int srow   = lane >> 3;
    const int swbyte = ((lane & 7) ^ srow) << 4;
    const int nt     = K / 64;

#define GEMM_STAGE(buf, k0)                                                        \
    {                                                                              \
        _Pragma("unroll")                                                          \
        for (int c = 0; c < 2; ++c) {                                              \
            int chunk = w * 2 + c;                                                 \
            int row   = chunk * 8 + srow;                                          \
            gload16((const char*)A + ((size_t)(m0 + row) * K + (k0)) * 2 + swbyte, \
                    sA[buf] + chunk * 1024);                                       \
            gload16((const char*)B + ((size_t)(n0 + row) * K + (k0)) * 2 + swbyte, \
                    sB[buf] + chunk * 1024);                                       \
        }                                                                          \
    }

    GEMM_STAGE(0, 0);
    __syncthreads();

    int cur = 0;
    for (int t = 0; t < nt; ++t) {
        if (t + 1 < nt) GEMM_STAGE(cur ^ 1, (t + 1) * 64);

#pragma unroll
        for (int k2 = 0; k2 < 2; ++k2) {
            bf16x8 af[2], bg[4];
#pragma unroll
            for (int f = 0; f < 2; ++f) {
                int row = wr * 32 + f * 16 + lr;
                af[f] = *(const bf16x8*)(sA[cur] + row * 128 +
                                         ((k2 * 64 + lg * 16) ^ ((row & 7) << 4)));
            }
#pragma unroll
            for (int g = 0; g < 4; ++g) {
                int row = wc * 64 + g * 16 + lr;
                bg[g] = *(const bf16x8*)(sB[cur] + row * 128 +
                                         ((k2 * 64 + lg * 16) ^ ((row & 7) << 4)));
            }
#pragma unroll
            for (int f = 0; f < 2; ++f)
#pragma unroll
                for (int g = 0; g < 4; ++g)
                    acc[f][g] = __builtin_amdgcn_mfma_f32_16x16x32_bf16(af[f], bg[g],
                                                                        acc[f][g], 0, 0, 0);
        }
        __syncthreads();
        cur ^= 1;
    }
#undef GEMM_STAGE

#pragma unroll
    for (int f = 0; f < 2; ++f)
#pragma unroll
        for (int g = 0; g < 4; ++g)
#pragma unroll
            for (int r = 0; r < 4; ++r)
                Cf[(size_t)(m0 + wr * 32 + f * 16 + lg * 4 + r) * N +
                   n0 + wc * 64 + g * 16 + lr] = acc[f][g][r];
}

// ---------------------------------------------------------------------------
// MFMA flash attention v10 (r12 version VERBATIM — proven 46.6us @ VGPR 64):
// unnormalized softmax, 4-buffer 2-ahead counted-vmcnt prefetch, no unroll.
// ---------------------------------------------------------------------------
__global__ __launch_bounds__(512) void attn_mfma(const unsigned short* __restrict__ qb,
                                                 const unsigned short* __restrict__ kb,
                                                 const unsigned short* __restrict__ vT,
                                                 unsigned short* __restrict__ ob) {
    __shared__ unsigned short sK[4][4096];   // 4 x 8 KB
    __shared__ unsigned short sV[4][4096];

    const int tid  = threadIdx.x;
    const int w    = tid >> 6;
    const int lane = tid & 63;
    const int ql   = lane & 31;
    const int hl   = lane >> 5;
    const int bh   = blockIdx.x;
    const int b    = bh >> 4, h = bh & 15;
    const int s0   = blockIdx.y * 256;
    const int NT   = SEQ / 64;               // 16

    const unsigned short* qrow = qb + ((size_t)(b * SEQ + s0 + w * 32 + ql) * DMODEL + h * 64);
    bf16x8 qf[4];
#pragma unroll
    for (int s = 0; s < 4; ++s)
        qf[s] = *(const bf16x8*)(qrow + 16 * s + 8 * hl);

    f32x16 acc0 = {}, acc1 = {};
    float l0 = 0.f, l1 = 0.f, l2 = 0.f, l3 = 0.f;

    const int srow = lane >> 3;
    const int ssw  = ((lane & 7) << 4) ^ (srow << 4);
    const int swz  = (ql & 7) << 4;
    int byos[4];
#pragma unroll
    for (int s = 0; s < 4; ++s) byos[s] = (32 * s + 16 * hl) ^ swz;

#define ATTN_STAGE(buf, kt)                                                          \
    {                                                                                \
        int row = w * 8 + srow;                                                      \
        gload16((const char*)kb +                                                    \
                    (((size_t)(b * SEQ + (kt) * 64 + row) * DMODEL + h * 64) * 2) + ssw, \
                (char*)sK[buf] + w * 1024);                                          \
        gload16((const char*)vT +                                                    \
                    (((size_t)(bh * 64 + row) * SEQ + (kt) * 64) * 2) + ssw,         \
                (char*)sV[buf] + w * 1024);                                          \
    }

    ATTN_STAGE(0, 0);
    ATTN_STAGE(1, 1);
    asm volatile("s_waitcnt vmcnt(2)" ::: "memory");
    __builtin_amdgcn_s_barrier();
    __builtin_amdgcn_sched_barrier(0);

    for (int kt = 0; kt < NT; ++kt) {
        const int cb = kt & 3;
        if (kt + 2 < NT) ATTN_STAGE((kt + 2) & 3, kt + 2);

        // ---- S^T = K·Q^T ----
        f32x16 st0 = {}, st1 = {};
        __builtin_amdgcn_s_setprio(1);
#pragma unroll
        for (int s = 0; s < 4; ++s) {
            bf16x8 kf0 = *(const bf16x8*)((const char*)sK[cb] + ql * 128 + byos[s]);
            bf16x8 kf1 = *(const bf16x8*)((const char*)sK[cb] + (32 + ql) * 128 + byos[s]);
            st0 = __builtin_amdgcn_mfma_f32_32x32x16_bf16(kf0, qf[s], st0, 0, 0, 0);
            st1 = __builtin_amdgcn_mfma_f32_32x32x16_bf16(kf1, qf[s], st1, 0, 0, 0);
        }
        __builtin_amdgcn_s_setprio(0);

        // ---- P = exp2(S) (unnormalized), pack + permlane-assemble ----
        bf16x8 pf[4];
#define TILE_P(stv, PF0, PF1)                                                       \
        {                                                                           \
            float p_[16];                                                           \
            _Pragma("unroll")                                                       \
            for (int i = 0; i < 16; ++i) p_[i] = fexp2(stv[i]);                     \
            _Pragma("unroll")                                                       \
            for (int i = 0; i < 4; ++i) {                                           \
                l0 += p_[4 * i];     l1 += p_[4 * i + 1];                           \
                l2 += p_[4 * i + 2]; l3 += p_[4 * i + 3];                           \
            }                                                                       \
            unsigned pk_[8];                                                        \
            _Pragma("unroll")                                                       \
            for (int i = 0; i < 8; ++i)                                             \
                asm("v_cvt_pk_bf16_f32 %0, %1, %2"                                  \
                    : "=v"(pk_[i]) : "v"(p_[2 * i]), "v"(p_[2 * i + 1]));           \
            auto rA = __builtin_amdgcn_permlane32_swap(pk_[0], pk_[2], false, false); \
            auto rB = __builtin_amdgcn_permlane32_swap(pk_[1], pk_[3], false, false); \
            auto rC = __builtin_amdgcn_permlane32_swap(pk_[4], pk_[6], false, false); \
            auto rD = __builtin_amdgcn_permlane32_swap(pk_[5], pk_[7], false, false); \
            uint32x4 f0, f1;                                                        \
            f0[0] = rA[0]; f0[1] = rB[0]; f0[2] = rA[1]; f0[3] = rB[1];             \
            f1[0] = rC[0]; f1[1] = rD[0]; f1[2] = rC[1]; f1[3] = rD[1];             \
            PF0 = __builtin_bit_cast(bf16x8, f0);                                   \
            PF1 = __builtin_bit_cast(bf16x8, f1);                                   \
        }
        TILE_P(st0, pf[0], pf[1]);
        TILE_P(st1, pf[2], pf[3]);
#undef TILE_P

        // ---- O^T += V^T·P^T ----
        __builtin_amdgcn_s_setprio(1);
#pragma unroll
        for (int s = 0; s < 4; ++s) {
            bf16x8 vf0 = *(const bf16x8*)((const char*)sV[cb] + ql * 128 + byos[s]);
            bf16x8 vf1 = *(const bf16x8*)((const char*)sV[cb] + (32 + ql) * 128 + byos[s]);
            acc0 = __builtin_amdgcn_mfma_f32_32x32x16_bf16(vf0, pf[s], acc0, 0, 0, 0);
            acc1 = __builtin_amdgcn_mfma_f32_32x32x16_bf16(vf1, pf[s], acc1, 0, 0, 0);
        }
        __builtin_amdgcn_s_setprio(0);

        if (kt + 2 < NT) { asm volatile("s_waitcnt vmcnt(2)" ::: "memory"); }
        else             { asm volatile("s_waitcnt vmcnt(0)" ::: "memory"); }
        __builtin_amdgcn_s_barrier();
        __builtin_amdgcn_sched_barrier(0);
    }
#undef ATTN_STAGE

    // ---- epilogue: combine l partials + cross-half, normalize, store ----
    float l_ = (l0 + l1) + (l2 + l3);
    float lf = l_ + __shfl_xor(l_, 32, 64);
    float inv = 1.f / lf;
    const size_t rowbase = (size_t)(b * SEQ + s0 + w * 32 + ql) * DMODEL + h * 64;
#pragma unroll
    for (int g = 0; g < 4; ++g) {
        short4v o0, o1;
#pragma unroll
        for (int r = 0; r < 4; ++r) {
            o0[r] = (short)f2bf(acc0[4 * g + r] * inv);
            o1[r] = (short)f2bf(acc1[4 * g + r] * inv);
        }
        int d = 8 * g + 4 * hl;
        *(short4v*)(ob + rowbase + d)      = o0;
        *(short4v*)(ob + rowbase + 32 + d) = o1;
    }
}

// ---------------------------------------------------------------------------
extern "C" void kernel_launch(void* const* d_in, const int* in_sizes, int n_in,
                              void* d_out, int out_size, void* d_ws, size_t ws_size,
                              hipStream_t stream) {
    const float* x       = (const float*)d_in[0];
    const float* W_split = (const float*)d_in[1];
    const float* W_out   = (const float*)d_in[2];
    const float* Wq      = (const float*)d_in[3];
    const float* Wk      = (const float*)d_in[4];
    const float* Wv      = (const float*)d_in[5];
    float* out = (float*)d_out;

    unsigned short* xb  = (unsigned short*)d_ws;                    // 16 MB
    unsigned short* obb = xb;                                       // alias (xb dead post-gemm1)
    unsigned short* wsb = xb + (size_t)ROWS * DMODEL;               // 2 MB
    unsigned short* wob = wsb + (size_t)DMODEL * DMODEL;            // 2 MB
    unsigned short* qbuf= wob + (size_t)DMODEL * DMODEL;            // 16 MB
    unsigned short* kbuf= qbuf + (size_t)ROWS * DMODEL;             // 16 MB
    unsigned short* vT  = kbuf + (size_t)ROWS * DMODEL;             // 16 MB
    unsigned short* wqb = vT + (size_t)ROWS * DMODEL;               // 128 KB
    unsigned short* wkb = wqb + (size_t)NHEAD * HD * HD;
    unsigned short* wvb = wkb + (size_t)NHEAD * HD * HD;

    // 0) all converts in one launch
    cvt_all<<<dim3(5216), dim3(256), 0, stream>>>(x, W_split, W_out, Wq, Wk, Wv,
                                                  xb, wsb, wob, wqb, wkb, wvb);
    // 1+2) fused GEMM1+QKV (r15 epilogue)
    gemm1_qkv<<<dim3(ROWS / 128, DMODEL / 128), dim3(512), 0, stream>>>(
        xb, wsb, wqb, wkb, wvb, qbuf, kbuf, vT);
    // 3) flash attention v10 (r12 verbatim)
    attn_mfma<<<dim3(BATCH * NHEAD, SEQ / 256), dim3(512), 0, stream>>>(qbuf, kbuf, vT, obb);
    // 4) out = obb @ W_out^T (f32)
    gemm_bf16<<<dim3(ROWS / 128, DMODEL / 128), dim3(512), 0, stream>>>(
        obb, wob, out, ROWS, DMODEL, DMODEL);
}